// Round 12
// baseline (257.616 us; speedup 1.0000x reference)
//
#include <hip/hip_runtime.h>
#include <math.h>

#define BATCH 8
#define NPTS 4096
#define CHAN 128
#define KNN 16
#define SPLIT 4
#define CHUNK (NPTS / SPLIT)   // 1024 candidates per chunk
#define ISPLIT 4               // quarters per chunk (1 wave each)
#define QCH (CHUNK / ISPLIT)   // 256 candidates per thread (8-bit local idx)
#define PTILE 64               // points per block
#define EPC 24                 // slow-path survivor buffer capacity

typedef unsigned long long u64;

// Monotone key: ascending u64 == (d2 ascending, idx ascending).
// Ties in d2 break toward lower index == lax.top_k stable order.
__device__ __forceinline__ u64 pack_key(float d2, int idx) {
  unsigned b = __float_as_uint(d2);
  b ^= (unsigned)((int)b >> 31) | 0x80000000u;  // order-preserving fp32 map
  return ((u64)b << 32) | (unsigned)idx;
}

// Reference d2: inner = ((x0*y0 + x1*y1) + x2*y2) fp32 no-fma (numpy einsum
// order); d2 = (sq_n + sq_m) - 2*inner. Bit-exact vs JAX reference.
__device__ __forceinline__ float d2_ref(float4 q, float ppx, float ppy,
                                        float ppz, float psq) {
  float inner = __fadd_rn(__fadd_rn(__fmul_rn(ppx, q.x), __fmul_rn(ppy, q.y)),
                          __fmul_rn(ppz, q.z));
  return __fsub_rn(__fadd_rn(psq, q.w), __fmul_rn(2.0f, inner));
}

// ----- u64 compare-exchange machinery ---------------------------------------
__device__ __forceinline__ void ce_asc(u64& x, u64& y) {
  bool sw = y < x;
  u64 lo = sw ? y : x;
  u64 hi = sw ? x : y;
  x = lo;
  y = hi;
}

// Batcher merge-exchange sort of 16 u64 keys, ascending. 63 CE.
__device__ __forceinline__ void batcher_sort16_u64(u64 a[16]) {
#define CE(i, j) ce_asc(a[i], a[j])
  CE(0, 8); CE(1, 9); CE(2, 10); CE(3, 11);
  CE(4, 12); CE(5, 13); CE(6, 14); CE(7, 15);
  CE(0, 4); CE(1, 5); CE(2, 6); CE(3, 7);
  CE(8, 12); CE(9, 13); CE(10, 14); CE(11, 15);
  CE(4, 8); CE(5, 9); CE(6, 10); CE(7, 11);
  CE(0, 2); CE(1, 3); CE(4, 6); CE(5, 7);
  CE(8, 10); CE(9, 11); CE(12, 14); CE(13, 15);
  CE(2, 8); CE(3, 9); CE(6, 12); CE(7, 13);
  CE(2, 4); CE(3, 5); CE(6, 8); CE(7, 9); CE(10, 12); CE(11, 13);
  CE(0, 1); CE(2, 3); CE(4, 5); CE(6, 7);
  CE(8, 9); CE(10, 11); CE(12, 13); CE(14, 15);
  CE(1, 8); CE(3, 10); CE(5, 12); CE(7, 14);
  CE(1, 4); CE(3, 6); CE(5, 8); CE(7, 10); CE(9, 12); CE(11, 14);
  CE(1, 2); CE(3, 4); CE(5, 6); CE(7, 8); CE(9, 10); CE(11, 12); CE(13, 14);
#undef CE
}

// Bitonic sort of 32 u64 keys, ascending. 240 CE (slow path only).
__device__ __forceinline__ void bitonic_sort32(u64 a[32]) {
#pragma unroll
  for (int k = 2; k <= 32; k <<= 1) {
#pragma unroll
    for (int j = k >> 1; j > 0; j >>= 1) {
#pragma unroll
      for (int i = 0; i < 32; ++i) {
        int l = i ^ j;
        if (l > i) {
          if ((i & k) == 0) ce_asc(a[i], a[l]);
          else              ce_asc(a[l], a[i]);
        }
      }
    }
  }
}

// T, A both sorted ascending. T <- lowest-16 of (T ∪ A), sorted ascending.
__device__ __forceinline__ void merge_keep16(u64 T[16], const u64 A[16]) {
  u64 nt[16];
#pragma unroll
  for (int i = 0; i < 16; ++i) {
    u64 a = A[15 - i];
    nt[i] = (a < T[i]) ? a : T[i];
  }
#pragma unroll
  for (int j = 8; j > 0; j >>= 1) {
#pragma unroll
    for (int i = 0; i < 16; ++i) {
      int l = i ^ j;
      if (l > i) ce_asc(nt[i], nt[l]);
    }
  }
#pragma unroll
  for (int i = 0; i < 16; ++i) T[i] = nt[i];
}

// ----- i32 packed-key machinery (hot phase 1) ------------------------------
// Packed key = (d2bits & ~255) | local_idx (8-bit). Signed-i32 ascending ==
// (trunc(d2), idx) ascending for all d2 >= 0 (negatives sort below all
// positives -> always selected -> exact epilogue fixes internal order).
// CE = v_min_i32 + v_max_i32 = 2 VALU.
__device__ __forceinline__ void ce_i32(int& x, int& y) {
  int lo = (x < y) ? x : y;
  int hi = (x < y) ? y : x;
  x = lo;
  y = hi;
}

// Batcher merge-exchange sort of 16 i32 keys, ascending. 63 CE.
__device__ __forceinline__ void batcher_sort16_i32(int a[16]) {
#define CE(i, j) ce_i32(a[i], a[j])
  CE(0, 8); CE(1, 9); CE(2, 10); CE(3, 11);
  CE(4, 12); CE(5, 13); CE(6, 14); CE(7, 15);
  CE(0, 4); CE(1, 5); CE(2, 6); CE(3, 7);
  CE(8, 12); CE(9, 13); CE(10, 14); CE(11, 15);
  CE(4, 8); CE(5, 9); CE(6, 10); CE(7, 11);
  CE(0, 2); CE(1, 3); CE(4, 6); CE(5, 7);
  CE(8, 10); CE(9, 11); CE(12, 14); CE(13, 15);
  CE(2, 8); CE(3, 9); CE(6, 12); CE(7, 13);
  CE(2, 4); CE(3, 5); CE(6, 8); CE(7, 9); CE(10, 12); CE(11, 13);
  CE(0, 1); CE(2, 3); CE(4, 5); CE(6, 7);
  CE(8, 9); CE(10, 11); CE(12, 13); CE(14, 15);
  CE(1, 8); CE(3, 10); CE(5, 12); CE(7, 14);
  CE(1, 4); CE(3, 6); CE(5, 8); CE(7, 10); CE(9, 12); CE(11, 14);
  CE(1, 2); CE(3, 4); CE(5, 6); CE(7, 8); CE(9, 10); CE(11, 12); CE(13, 14);
#undef CE
}

// T, A sorted ascending (i32). T <- lowest-16 of (T ∪ A). 80 VALU.
__device__ __forceinline__ void merge_keep16_i32(int T[16], const int A[16]) {
  int nt[16];
#pragma unroll
  for (int i = 0; i < 16; ++i) {
    int a = A[15 - i];
    nt[i] = (a < T[i]) ? a : T[i];
  }
#pragma unroll
  for (int j = 8; j > 0; j >>= 1) {
#pragma unroll
    for (int i = 0; i < 16; ++i) {
      int l = i ^ j;
      if (l > i) ce_i32(nt[i], nt[l]);
    }
  }
#pragma unroll
  for (int i = 0; i < 16; ++i) T[i] = nt[i];
}

// ---------------------------------------------------------------------------
// Kernel 1a: per-chunk 16-NN partials as sorted u64 keys.
// Round-12 RESIDENCY EXPERIMENT: across R6-R11 the occupancy counter never
// exceeded ~34% with 512-thread blocks (measured ~8-9 waves/CU ~= ONE block)
// no matter the grid/LDS/caps, and knn runs at 3x its 44us VALU issue floor
// (SIMDs ~68% idle). Hypothesis: 512-thr workgroups fail to co-reside.
// Test: same algorithm in 256-thread blocks (64 pts x 4 quarters, one WAVE
// per quarter), LDS 24576 B -> 6 blocks/CU theoretical = 24 waves/CU.
// Grid: B x (N/64) x SPLIT = 2048 blocks. Hot loop byte-identical to the
// proven R6-R11 form (QCH=256, 8-bit packed keys, r17 guard, u8 scratch).
// Exactness: tau superset + exact r17 guard; fast path rebuilds exact u64
// keys; slow path rescans {trunc <= tau} -> bit-identical to full-u64 path.
// ---------------------------------------------------------------------------
__global__ __launch_bounds__(256) void knn_partial_kernel(
    const float* __restrict__ x, u64* __restrict__ pkey) {
  const int s = blockIdx.x % SPLIT;
  const int ntile = (blockIdx.x / SPLIT) % (NPTS / PTILE);
  const int b = blockIdx.x / (SPLIT * (NPTS / PTILE));
  const int p = threadIdx.x & (PTILE - 1);
  const int q4 = threadIdx.x >> 6;  // quarter 0..3 == wave id
  __shared__ float4 xs[CHUNK];      // 16 KB (x, y, z, sq)
  __shared__ u64 ubuf[1024];        // 8 KB: u8 scratch(6K) ∪ staging[16][64]

  const float* xb = x + (size_t)b * 3 * NPTS;
  for (int i = threadIdx.x; i < CHUNK; i += 256) {
    int gm = s * CHUNK + i;
    float px = xb[gm];
    float py = xb[NPTS + gm];
    float pz = xb[2 * NPTS + gm];
    float sq = __fadd_rn(__fadd_rn(__fmul_rn(px, px), __fmul_rn(py, py)),
                         __fmul_rn(pz, pz));
    xs[i] = make_float4(px, py, pz, sq);
  }

  const int n = ntile * PTILE + p;
  float ppx = xb[n];
  float ppy = xb[NPTS + n];
  float ppz = xb[2 * NPTS + n];
  float psq = __fadd_rn(__fadd_rn(__fmul_rn(ppx, ppx), __fmul_rn(ppy, ppy)),
                        __fmul_rn(ppz, ppz));
  __syncthreads();

  const int cbase = q4 * QCH;

  // ---- Phase 1: top-16 packed keys + exact 17th (r17) ----
  int T[16];
#pragma unroll
  for (int i = 0; i < 16; ++i) T[i] = 0x7FFFFFFF;  // sentinel > any real key
  int r17 = 0x7FFFFFFF;

#pragma unroll 1
  for (int base = 0; base < QCH; base += 16) {
    int A[16];
#pragma unroll
    for (int t = 0; t < 16; ++t) {
      float4 q = xs[cbase + base + t];
      int bits = __float_as_int(d2_ref(q, ppx, ppy, ppz, psq));
      A[t] = (bits & 0xFFFFFF00) | (base + t);
    }
    batcher_sort16_i32(A);
    // 17th smallest of (T ∪ A), both sorted: min_i max(T[i], A[15-i])
    int u[16];
#pragma unroll
    for (int i = 0; i < 16; ++i) {
      int a = A[15 - i];
      u[i] = (T[i] < a) ? a : T[i];  // max
    }
#pragma unroll
    for (int w = 8; w > 0; w >>= 1) {
#pragma unroll
      for (int i = 0; i < 16; ++i) {
        if (i < w) u[i] = (u[i] < u[i + w]) ? u[i] : u[i + w];  // min
      }
    }
    r17 = (r17 < u[0]) ? r17 : u[0];
    merge_keep16_i32(T, A);
  }

  const int tau = T[15] & 0xFFFFFF00;
  const bool slow = ((r17 & 0xFFFFFF00) == tau);

  // ---- Epilogue: exact u64 top-16 keys ----
  u64 K[16];
  if (!slow) {
    // fast: T is the exact top-16 set; rebuild exact keys, sort.
#pragma unroll
    for (int j = 0; j < 16; ++j) {
      int loc = cbase + (T[j] & 255);
      float4 q = xs[loc];
      float d2 = d2_ref(q, ppx, ppy, ppz, psq);
      K[j] = pack_key(d2, s * CHUNK + loc);
    }
    batcher_sort16_u64(K);
  } else {
    // slow: collect all candidates with trunc <= tau, exact sort, keep 16.
    unsigned char* myb =
        reinterpret_cast<unsigned char*>(ubuf) + (unsigned)threadIdx.x * EPC;
    int cnt = 0;
#pragma unroll 4
    for (int m = 0; m < QCH; ++m) {
      float4 q = xs[cbase + m];
      int tb = __float_as_int(d2_ref(q, ppx, ppy, ppz, psq)) & 0xFFFFFF00;
      if (tb <= tau) {
        myb[cnt < EPC - 1 ? cnt : EPC - 1] = (unsigned char)m;
        ++cnt;
      }
    }
    u64 KK[32];
#pragma unroll
    for (int j = 0; j < EPC; ++j) {
      int loc = cbase + myb[j];  // u8 always < QCH; garbage past cnt masked
      float4 q = xs[loc];
      float d2 = d2_ref(q, ppx, ppy, ppz, psq);
      u64 k = pack_key(d2, s * CHUNK + loc);
      KK[j] = (j < cnt) ? k : ~0ull;
    }
#pragma unroll
    for (int j = EPC; j < 32; ++j) KK[j] = ~0ull;
    bitonic_sort32(KK);
#pragma unroll
    for (int j = 0; j < 16; ++j) K[j] = KK[j];
  }

  // ---- combine quarters: chain q1,q2,q3 stage -> q0 merges ----
  __syncthreads();  // scratch lifetime ends; staging view reuses ubuf
  u64(*L)[PTILE] = reinterpret_cast<u64(*)[PTILE]>(ubuf);  // [16][64]
#pragma unroll 1
  for (int r = 1; r <= 3; ++r) {
    if (q4 == r) {
#pragma unroll
      for (int j = 0; j < 16; ++j) L[j][p] = K[j];
    }
    __syncthreads();
    if (q4 == 0) {
      u64 A64[16];
#pragma unroll
      for (int j = 0; j < 16; ++j) A64[j] = L[j][p];
      merge_keep16(K, A64);
    }
    __syncthreads();
  }
  if (q4 == 0) {
    u64* pb = pkey + ((size_t)(b * SPLIT + s) * KNN) * NPTS + n;
#pragma unroll
    for (int j = 0; j < 16; ++j) pb[(size_t)j * NPTS] = K[j];
  }
}

// ---------------------------------------------------------------------------
// Kernel 1b: merge SPLIT sorted key lists -> global top-16, then fp32 score.
// R10's proven 4-threads-per-point form (lane s = t&3 owns list s; two
// shfl_xor+merge rounds converge all 4 lanes to the identical sorted global
// top-16; per-dim scoring on lanes 0..2, recombined in numpy pairwise order).
// grid: BATCH*(NPTS/64) = 512 blocks x 256.
// ---------------------------------------------------------------------------
__global__ __launch_bounds__(256) void merge_score_kernel(
    const float* __restrict__ x, const u64* __restrict__ pkey,
    float* __restrict__ score) {
  const int tile = blockIdx.x % (NPTS / 64);
  const int b = blockIdx.x / (NPTS / 64);
  const int g = threadIdx.x >> 2;  // point within tile [0,64)
  const int s = threadIdx.x & 3;   // split list
  const int n = tile * 64 + g;

  u64 T[16];
  {
    const u64* pb = pkey + ((size_t)(b * SPLIT + s) * KNN) * NPTS + n;
#pragma unroll
    for (int j = 0; j < 16; ++j) T[j] = pb[(size_t)j * NPTS];
  }

  u64 A[16];
#pragma unroll
  for (int j = 0; j < 16; ++j)
    A[j] = (u64)__shfl_xor((long long)T[j], 1);
  merge_keep16(T, A);
#pragma unroll
  for (int j = 0; j < 16; ++j)
    A[j] = (u64)__shfl_xor((long long)T[j], 2);
  merge_keep16(T, A);
  // all 4 lanes now hold the identical global sorted top-16.

  const float* xb = x + (size_t)b * 3 * NPTS;
  float P = 0.0f;
  if (s < 3) {
    const float* xd = xb + (size_t)s * NPTS;
    const float pc = xd[n];
    float r[8];
#pragma unroll
    for (int j = 0; j < 8; ++j) {
      float c0 = xd[(int)(unsigned)T[j]];
      float c1 = xd[(int)(unsigned)T[j + 8]];
      float e0 = __fsub_rn(c0, pc);
      float e1 = __fsub_rn(c1, pc);
      r[j] = __fadd_rn(__fmul_rn(e0, e0), __fmul_rn(e1, e1));
    }
    float t0 = __fadd_rn(r[0], r[1]);
    float t1 = __fadd_rn(r[2], r[3]);
    float t2 = __fadd_rn(r[4], r[5]);
    float t3 = __fadd_rn(r[6], r[7]);
    P = __fadd_rn(__fadd_rn(t0, t1), __fadd_rn(t2, t3));
  }
  float Pa = __shfl_xor(P, 1);
  float Pb = __shfl_xor(P, 2);
  if (s == 0)
    score[(size_t)b * NPTS + n] = __fadd_rn(__fadd_rn(P, Pa), Pb);
}

// ---------------------------------------------------------------------------
// Kernel 2 (fused rank + scatter, atomics-free; R11's proven form): block =
// 128 points x 2 scan-halves. rank(n) = #{m: s[m]>s[n] or (s[m]==s[n], m<n)}
// is a total order -> unique c -> collision-free direct scatter == stable
// desc argsort. grid: BATCH*(NPTS/128) = 256 blocks.
// ---------------------------------------------------------------------------
__global__ __launch_bounds__(256) void rank_scatter_kernel(
    const float* __restrict__ score, int* __restrict__ sel, int npts) {
  const int tile = blockIdx.x % (NPTS / 128);
  const int b = blockIdx.x / (NPTS / 128);
  const int p = threadIdx.x & 127;
  const int h = threadIdx.x >> 7;
  __shared__ float4 sv[NPTS / 4];  // 16 KB
  __shared__ int cpart[128];

  const float* sb = score + (size_t)b * NPTS;
  const float4* sb4 = reinterpret_cast<const float4*>(sb);
  for (int i = threadIdx.x; i < NPTS / 4; i += 256) sv[i] = sb4[i];

  const int n = tile * 128 + p;
  const float sn = sb[n];
  __syncthreads();

  int c = 0;
  const int v0 = h * (NPTS / 8);
#pragma unroll 4
  for (int v = v0; v < v0 + NPTS / 8; ++v) {
    float4 f = sv[v];
    int gm = 4 * v;
    c += (f.x > sn) || (f.x == sn && gm < n);
    c += (f.y > sn) || (f.y == sn && gm + 1 < n);
    c += (f.z > sn) || (f.z == sn && gm + 2 < n);
    c += (f.w > sn) || (f.w == sn && gm + 3 < n);
  }
  if (h == 1) cpart[p] = c;
  __syncthreads();
  if (h == 0) {
    c += cpart[p];
    if (c < npts) sel[(size_t)b * npts + c] = n;
  }
}

// ---------------------------------------------------------------------------
// Kernel 3: gather xyz then features into the concatenated flat output.
// ---------------------------------------------------------------------------
__global__ __launch_bounds__(256) void gather_kernel(
    const float* __restrict__ x, const float* __restrict__ y,
    const int* __restrict__ sel, float* __restrict__ out, int npts,
    int total0, int total) {
  int tid = blockIdx.x * blockDim.x + threadIdx.x;
  if (tid >= total) return;
  if (tid < total0) {
    int j = tid % npts;
    int rest = tid / npts;
    int d = rest % 3;
    int b = rest / 3;
    int src = sel[b * npts + j];
    out[tid] = x[((size_t)b * 3 + d) * NPTS + src];
  } else {
    int t = tid - total0;
    int j = t % npts;
    int rest = t / npts;
    int c = rest % CHAN;
    int b = rest / CHAN;
    int src = sel[b * npts + j];
    out[tid] = y[((size_t)b * CHAN + c) * NPTS + src];
  }
}

extern "C" void kernel_launch(void* const* d_in, const int* in_sizes, int n_in,
                              void* d_out, int out_size, void* d_ws,
                              size_t ws_size, hipStream_t stream) {
  const float* x = (const float*)d_in[0];
  const float* y = (const float*)d_in[1];
  float* out = (float*)d_out;

  const int npts = out_size / (BATCH * (3 + CHAN));

  // workspace layout:
  char* w = (char*)d_ws;
  u64* pkey = (u64*)w;                       // B*S*16*N u64 = 16.78 MB
  w += sizeof(u64) * (size_t)BATCH * SPLIT * KNN * NPTS;
  float* score = (float*)w;                  // B*N f32
  w += sizeof(float) * (size_t)BATCH * NPTS;
  int* sel = (int*)w;                        // B*npts i32

  knn_partial_kernel<<<BATCH * (NPTS / PTILE) * SPLIT, 256, 0, stream>>>(
      x, pkey);
  merge_score_kernel<<<BATCH * (NPTS / 64), 256, 0, stream>>>(x, pkey, score);
  rank_scatter_kernel<<<BATCH * (NPTS / 128), 256, 0, stream>>>(score, sel,
                                                                npts);
  const int total0 = BATCH * 3 * npts;
  gather_kernel<<<(out_size + 255) / 256, 256, 0, stream>>>(
      x, y, sel, out, npts, total0, out_size);
}

// Round 13
// 254.930 us; speedup vs baseline: 1.0105x; 1.0105x over previous
//
#include <hip/hip_runtime.h>
#include <math.h>

#define BATCH 8
#define NPTS 4096
#define CHAN 128
#define KNN 16
#define SPLIT 4
#define CHUNK (NPTS / SPLIT)   // 1024 candidates per chunk
#define ISPLIT 4               // quarters per chunk (1 wave each)
#define QCH (CHUNK / ISPLIT)   // 256 candidates per wave (8-bit local idx)
#define PTILE 64               // points per block
#define EPC 24                 // slow-path survivor buffer capacity

typedef unsigned long long u64;

// Monotone key: ascending u64 == (d2 ascending, idx ascending).
// Ties in d2 break toward lower index == lax.top_k stable order.
__device__ __forceinline__ u64 pack_key(float d2, int idx) {
  unsigned b = __float_as_uint(d2);
  b ^= (unsigned)((int)b >> 31) | 0x80000000u;  // order-preserving fp32 map
  return ((u64)b << 32) | (unsigned)idx;
}

// Reference d2: inner = ((x0*y0 + x1*y1) + x2*y2) fp32 no-fma (numpy einsum
// order); d2 = (sq_n + sq_m) - 2*inner. Bit-exact vs JAX reference.
__device__ __forceinline__ float d2_ref(float4 q, float ppx, float ppy,
                                        float ppz, float psq) {
  float inner = __fadd_rn(__fadd_rn(__fmul_rn(ppx, q.x), __fmul_rn(ppy, q.y)),
                          __fmul_rn(ppz, q.z));
  return __fsub_rn(__fadd_rn(psq, q.w), __fmul_rn(2.0f, inner));
}

// ----- u64 compare-exchange machinery ---------------------------------------
__device__ __forceinline__ void ce_asc(u64& x, u64& y) {
  bool sw = y < x;
  u64 lo = sw ? y : x;
  u64 hi = sw ? x : y;
  x = lo;
  y = hi;
}

// Batcher merge-exchange sort of 16 u64 keys, ascending. 63 CE.
__device__ __forceinline__ void batcher_sort16_u64(u64 a[16]) {
#define CE(i, j) ce_asc(a[i], a[j])
  CE(0, 8); CE(1, 9); CE(2, 10); CE(3, 11);
  CE(4, 12); CE(5, 13); CE(6, 14); CE(7, 15);
  CE(0, 4); CE(1, 5); CE(2, 6); CE(3, 7);
  CE(8, 12); CE(9, 13); CE(10, 14); CE(11, 15);
  CE(4, 8); CE(5, 9); CE(6, 10); CE(7, 11);
  CE(0, 2); CE(1, 3); CE(4, 6); CE(5, 7);
  CE(8, 10); CE(9, 11); CE(12, 14); CE(13, 15);
  CE(2, 8); CE(3, 9); CE(6, 12); CE(7, 13);
  CE(2, 4); CE(3, 5); CE(6, 8); CE(7, 9); CE(10, 12); CE(11, 13);
  CE(0, 1); CE(2, 3); CE(4, 5); CE(6, 7);
  CE(8, 9); CE(10, 11); CE(12, 13); CE(14, 15);
  CE(1, 8); CE(3, 10); CE(5, 12); CE(7, 14);
  CE(1, 4); CE(3, 6); CE(5, 8); CE(7, 10); CE(9, 12); CE(11, 14);
  CE(1, 2); CE(3, 4); CE(5, 6); CE(7, 8); CE(9, 10); CE(11, 12); CE(13, 14);
#undef CE
}

// Bitonic sort of 32 u64 keys, ascending. 240 CE (slow path only).
__device__ __forceinline__ void bitonic_sort32(u64 a[32]) {
#pragma unroll
  for (int k = 2; k <= 32; k <<= 1) {
#pragma unroll
    for (int j = k >> 1; j > 0; j >>= 1) {
#pragma unroll
      for (int i = 0; i < 32; ++i) {
        int l = i ^ j;
        if (l > i) {
          if ((i & k) == 0) ce_asc(a[i], a[l]);
          else              ce_asc(a[l], a[i]);
        }
      }
    }
  }
}

// T, A both sorted ascending. T <- lowest-16 of (T ∪ A), sorted ascending.
__device__ __forceinline__ void merge_keep16(u64 T[16], const u64 A[16]) {
  u64 nt[16];
#pragma unroll
  for (int i = 0; i < 16; ++i) {
    u64 a = A[15 - i];
    nt[i] = (a < T[i]) ? a : T[i];
  }
#pragma unroll
  for (int j = 8; j > 0; j >>= 1) {
#pragma unroll
    for (int i = 0; i < 16; ++i) {
      int l = i ^ j;
      if (l > i) ce_asc(nt[i], nt[l]);
    }
  }
#pragma unroll
  for (int i = 0; i < 16; ++i) T[i] = nt[i];
}

// ----- i32 packed-key machinery (hot phase 1) ------------------------------
// Packed key = (d2bits & ~255) | local_idx (8-bit). Signed-i32 ascending ==
// (trunc(d2), idx) ascending for all d2 >= 0 (negatives sort below all
// positives -> always selected -> exact epilogue fixes internal order).
// Explicit min()/max() -> v_min_i32 + v_max_i32 (2 VALU), never cmp+cndmask.
__device__ __forceinline__ void ce_i32(int& x, int& y) {
  int lo = min(x, y);
  int hi = max(x, y);
  x = lo;
  y = hi;
}

// Batcher merge-exchange sort of 16 i32 keys, ascending. 63 CE.
__device__ __forceinline__ void batcher_sort16_i32(int a[16]) {
#define CE(i, j) ce_i32(a[i], a[j])
  CE(0, 8); CE(1, 9); CE(2, 10); CE(3, 11);
  CE(4, 12); CE(5, 13); CE(6, 14); CE(7, 15);
  CE(0, 4); CE(1, 5); CE(2, 6); CE(3, 7);
  CE(8, 12); CE(9, 13); CE(10, 14); CE(11, 15);
  CE(4, 8); CE(5, 9); CE(6, 10); CE(7, 11);
  CE(0, 2); CE(1, 3); CE(4, 6); CE(5, 7);
  CE(8, 10); CE(9, 11); CE(12, 14); CE(13, 15);
  CE(2, 8); CE(3, 9); CE(6, 12); CE(7, 13);
  CE(2, 4); CE(3, 5); CE(6, 8); CE(7, 9); CE(10, 12); CE(11, 13);
  CE(0, 1); CE(2, 3); CE(4, 5); CE(6, 7);
  CE(8, 9); CE(10, 11); CE(12, 13); CE(14, 15);
  CE(1, 8); CE(3, 10); CE(5, 12); CE(7, 14);
  CE(1, 4); CE(3, 6); CE(5, 8); CE(7, 10); CE(9, 12); CE(11, 14);
  CE(1, 2); CE(3, 4); CE(5, 6); CE(7, 8); CE(9, 10); CE(11, 12); CE(13, 14);
#undef CE
}

// T, A sorted ascending (i32). T <- lowest-16 of (T ∪ A). 80 VALU.
__device__ __forceinline__ void merge_keep16_i32(int T[16], const int A[16]) {
  int nt[16];
#pragma unroll
  for (int i = 0; i < 16; ++i) nt[i] = min(A[15 - i], T[i]);
#pragma unroll
  for (int j = 8; j > 0; j >>= 1) {
#pragma unroll
    for (int i = 0; i < 16; ++i) {
      int l = i ^ j;
      if (l > i) ce_i32(nt[i], nt[l]);
    }
  }
#pragma unroll
  for (int i = 0; i < 16; ++i) T[i] = nt[i];
}

// ---------------------------------------------------------------------------
// Kernel 0: pack x (B,3,N planar) -> packed[b][m] = (x, y, z, sq) float4.
// sq uses the exact rounding chain of the reference -> downstream bit-exact.
// ---------------------------------------------------------------------------
__global__ __launch_bounds__(256) void pack_kernel(
    const float* __restrict__ x, float4* __restrict__ packed) {
  int t = blockIdx.x * 256 + threadIdx.x;  // over BATCH*NPTS
  int b = t / NPTS;
  int m = t % NPTS;
  const float* xb = x + (size_t)b * 3 * NPTS;
  float px = xb[m];
  float py = xb[NPTS + m];
  float pz = xb[2 * NPTS + m];
  float sq = __fadd_rn(__fadd_rn(__fmul_rn(px, px), __fmul_rn(py, py)),
                       __fmul_rn(pz, pz));
  packed[t] = make_float4(px, py, pz, sq);
}

// ---------------------------------------------------------------------------
// Kernel 1a: per-chunk 16-NN partials as sorted u64 keys.
// Round-13: LDS OUT OF THE HOT LOOP. R12 accounting: real VALU ~40us and
// LDS-pipe ~43us both at ~35% util at dur=126us -- every hot-loop candidate
// read was a wave-uniform ds_read_b128 broadcast (256/wave) through the
// single per-CU LDS pipe, fed by a staged copy + barrier. Wave-uniform data
// doesn't need LDS: read candidates straight from the packed global buffer
// at a readfirstlane-pinned uniform base -> scalar/L1-broadcast loads on the
// SMEM/VMEM pipes; LDS shrinks to 8 KB (combine staging ∪ slow scratch);
// phase 1 + epilogue run with ZERO barriers. Epilogue per-lane gathers hit
// the same 4 KB window in L1. Hot-loop network unchanged (proven exact).
// grid: B x (N/64) x SPLIT = 2048 blocks x 256 thr.
// Exactness: tau superset + exact r17 guard; fast path rebuilds exact u64
// keys; slow path rescans {trunc <= tau} -> bit-identical to full-u64 path.
// ---------------------------------------------------------------------------
__global__ __launch_bounds__(256) void knn_partial_kernel(
    const float4* __restrict__ packed, u64* __restrict__ pkey) {
  const int s = blockIdx.x % SPLIT;
  const int ntile = (blockIdx.x / SPLIT) % (NPTS / PTILE);
  const int b = blockIdx.x / (SPLIT * (NPTS / PTILE));
  const int p = threadIdx.x & (PTILE - 1);
  const int q4 = threadIdx.x >> 6;  // quarter 0..3 == wave id
  __shared__ u64 ubuf[1024];        // 8 KB: u8 scratch(6K) ∪ staging[16][64]

  const float4* pb4 = packed + (size_t)b * NPTS;
  const int n = ntile * PTILE + p;
  float4 pp = pb4[n];  // per-lane coalesced
  const float ppx = pp.x, ppy = pp.y, ppz = pp.z, psq = pp.w;

  // wave-uniform candidate window base (provably uniform via readfirstlane)
  const int cbase = __builtin_amdgcn_readfirstlane(s * CHUNK + q4 * QCH);
  const float4* win = pb4 + cbase;

  // ---- Phase 1: top-16 packed keys + exact 17th (r17); no LDS, no bar ----
  int T[16];
#pragma unroll
  for (int i = 0; i < 16; ++i) T[i] = 0x7FFFFFFF;  // sentinel > any real key
  int r17 = 0x7FFFFFFF;

#pragma unroll 1
  for (int base = 0; base < QCH; base += 16) {
    int A[16];
#pragma unroll
    for (int t = 0; t < 16; ++t) {
      float4 q = win[base + t];  // uniform addr -> s_load / L1 broadcast
      int bits = __float_as_int(d2_ref(q, ppx, ppy, ppz, psq));
      A[t] = (bits & 0xFFFFFF00) | (base + t);
    }
    batcher_sort16_i32(A);
    // 17th smallest of (T ∪ A), both sorted: min_i max(T[i], A[15-i])
    int u[16];
#pragma unroll
    for (int i = 0; i < 16; ++i) u[i] = max(T[i], A[15 - i]);
#pragma unroll
    for (int w = 8; w > 0; w >>= 1) {
#pragma unroll
      for (int i = 0; i < 16; ++i) {
        if (i < w) u[i] = min(u[i], u[i + w]);
      }
    }
    r17 = min(r17, u[0]);
    merge_keep16_i32(T, A);
  }

  const int tau = T[15] & 0xFFFFFF00;
  const bool slow = ((r17 & 0xFFFFFF00) == tau);

  // ---- Epilogue: exact u64 top-16 keys (gathers hit L1 window) ----
  u64 K[16];
  if (!slow) {
#pragma unroll
    for (int j = 0; j < 16; ++j) {
      int loc = T[j] & 255;
      float4 q = win[loc];
      float d2 = d2_ref(q, ppx, ppy, ppz, psq);
      K[j] = pack_key(d2, cbase + loc);
    }
    batcher_sort16_u64(K);
  } else {
    unsigned char* myb =
        reinterpret_cast<unsigned char*>(ubuf) + (unsigned)threadIdx.x * EPC;
    int cnt = 0;
#pragma unroll 4
    for (int m = 0; m < QCH; ++m) {
      float4 q = win[m];  // uniform
      int tb = __float_as_int(d2_ref(q, ppx, ppy, ppz, psq)) & 0xFFFFFF00;
      if (tb <= tau) {
        myb[cnt < EPC - 1 ? cnt : EPC - 1] = (unsigned char)m;
        ++cnt;
      }
    }
    u64 KK[32];
#pragma unroll
    for (int j = 0; j < EPC; ++j) {
      int loc = myb[j];  // u8 always < QCH; garbage past cnt masked below
      float4 q = win[loc];
      float d2 = d2_ref(q, ppx, ppy, ppz, psq);
      u64 k = pack_key(d2, cbase + loc);
      KK[j] = (j < cnt) ? k : ~0ull;
    }
#pragma unroll
    for (int j = EPC; j < 32; ++j) KK[j] = ~0ull;
    bitonic_sort32(KK);
#pragma unroll
    for (int j = 0; j < 16; ++j) K[j] = KK[j];
  }

  // ---- combine quarters: chain q1,q2,q3 stage -> q0 merges ----
  __syncthreads();  // scratch lifetime ends; staging view reuses ubuf
  u64(*L)[PTILE] = reinterpret_cast<u64(*)[PTILE]>(ubuf);  // [16][64]
#pragma unroll 1
  for (int r = 1; r <= 3; ++r) {
    if (q4 == r) {
#pragma unroll
      for (int j = 0; j < 16; ++j) L[j][p] = K[j];
    }
    __syncthreads();
    if (q4 == 0) {
      u64 A64[16];
#pragma unroll
      for (int j = 0; j < 16; ++j) A64[j] = L[j][p];
      merge_keep16(K, A64);
    }
    __syncthreads();
  }
  if (q4 == 0) {
    u64* pb = pkey + ((size_t)(b * SPLIT + s) * KNN) * NPTS + n;
#pragma unroll
    for (int j = 0; j < 16; ++j) pb[(size_t)j * NPTS] = K[j];
  }
}

// ---------------------------------------------------------------------------
// Kernel 1b: merge SPLIT sorted key lists -> global top-16, then fp32 score.
// R10's proven 4-threads-per-point form (lane s = t&3 owns list s; two
// shfl_xor+merge rounds converge all 4 lanes to the identical sorted global
// top-16; per-dim scoring on lanes 0..2, recombined in numpy pairwise order).
// grid: BATCH*(NPTS/64) = 512 blocks x 256.
// ---------------------------------------------------------------------------
__global__ __launch_bounds__(256) void merge_score_kernel(
    const float* __restrict__ x, const u64* __restrict__ pkey,
    float* __restrict__ score) {
  const int tile = blockIdx.x % (NPTS / 64);
  const int b = blockIdx.x / (NPTS / 64);
  const int g = threadIdx.x >> 2;  // point within tile [0,64)
  const int s = threadIdx.x & 3;   // split list
  const int n = tile * 64 + g;

  u64 T[16];
  {
    const u64* pb = pkey + ((size_t)(b * SPLIT + s) * KNN) * NPTS + n;
#pragma unroll
    for (int j = 0; j < 16; ++j) T[j] = pb[(size_t)j * NPTS];
  }

  u64 A[16];
#pragma unroll
  for (int j = 0; j < 16; ++j)
    A[j] = (u64)__shfl_xor((long long)T[j], 1);
  merge_keep16(T, A);
#pragma unroll
  for (int j = 0; j < 16; ++j)
    A[j] = (u64)__shfl_xor((long long)T[j], 2);
  merge_keep16(T, A);
  // all 4 lanes now hold the identical global sorted top-16.

  const float* xb = x + (size_t)b * 3 * NPTS;
  float P = 0.0f;
  if (s < 3) {
    const float* xd = xb + (size_t)s * NPTS;
    const float pc = xd[n];
    float r[8];
#pragma unroll
    for (int j = 0; j < 8; ++j) {
      float c0 = xd[(int)(unsigned)T[j]];
      float c1 = xd[(int)(unsigned)T[j + 8]];
      float e0 = __fsub_rn(c0, pc);
      float e1 = __fsub_rn(c1, pc);
      r[j] = __fadd_rn(__fmul_rn(e0, e0), __fmul_rn(e1, e1));
    }
    float t0 = __fadd_rn(r[0], r[1]);
    float t1 = __fadd_rn(r[2], r[3]);
    float t2 = __fadd_rn(r[4], r[5]);
    float t3 = __fadd_rn(r[6], r[7]);
    P = __fadd_rn(__fadd_rn(t0, t1), __fadd_rn(t2, t3));
  }
  float Pa = __shfl_xor(P, 1);
  float Pb = __shfl_xor(P, 2);
  if (s == 0)
    score[(size_t)b * NPTS + n] = __fadd_rn(__fadd_rn(P, Pa), Pb);
}

// ---------------------------------------------------------------------------
// Kernel 2 (fused rank + scatter, atomics-free; R11's proven form): block =
// 128 points x 2 scan-halves. rank(n) = #{m: s[m]>s[n] or (s[m]==s[n], m<n)}
// is a total order -> unique c -> collision-free direct scatter == stable
// desc argsort. grid: BATCH*(NPTS/128) = 256 blocks.
// ---------------------------------------------------------------------------
__global__ __launch_bounds__(256) void rank_scatter_kernel(
    const float* __restrict__ score, int* __restrict__ sel, int npts) {
  const int tile = blockIdx.x % (NPTS / 128);
  const int b = blockIdx.x / (NPTS / 128);
  const int p = threadIdx.x & 127;
  const int h = threadIdx.x >> 7;
  __shared__ float4 sv[NPTS / 4];  // 16 KB
  __shared__ int cpart[128];

  const float* sb = score + (size_t)b * NPTS;
  const float4* sb4 = reinterpret_cast<const float4*>(sb);
  for (int i = threadIdx.x; i < NPTS / 4; i += 256) sv[i] = sb4[i];

  const int n = tile * 128 + p;
  const float sn = sb[n];
  __syncthreads();

  int c = 0;
  const int v0 = h * (NPTS / 8);
#pragma unroll 4
  for (int v = v0; v < v0 + NPTS / 8; ++v) {
    float4 f = sv[v];
    int gm = 4 * v;
    c += (f.x > sn) || (f.x == sn && gm < n);
    c += (f.y > sn) || (f.y == sn && gm + 1 < n);
    c += (f.z > sn) || (f.z == sn && gm + 2 < n);
    c += (f.w > sn) || (f.w == sn && gm + 3 < n);
  }
  if (h == 1) cpart[p] = c;
  __syncthreads();
  if (h == 0) {
    c += cpart[p];
    if (c < npts) sel[(size_t)b * npts + c] = n;
  }
}

// ---------------------------------------------------------------------------
// Kernel 3: gather xyz then features into the concatenated flat output.
// ---------------------------------------------------------------------------
__global__ __launch_bounds__(256) void gather_kernel(
    const float* __restrict__ x, const float* __restrict__ y,
    const int* __restrict__ sel, float* __restrict__ out, int npts,
    int total0, int total) {
  int tid = blockIdx.x * blockDim.x + threadIdx.x;
  if (tid >= total) return;
  if (tid < total0) {
    int j = tid % npts;
    int rest = tid / npts;
    int d = rest % 3;
    int b = rest / 3;
    int src = sel[b * npts + j];
    out[tid] = x[((size_t)b * 3 + d) * NPTS + src];
  } else {
    int t = tid - total0;
    int j = t % npts;
    int rest = t / npts;
    int c = rest % CHAN;
    int b = rest / CHAN;
    int src = sel[b * npts + j];
    out[tid] = y[((size_t)b * CHAN + c) * NPTS + src];
  }
}

extern "C" void kernel_launch(void* const* d_in, const int* in_sizes, int n_in,
                              void* d_out, int out_size, void* d_ws,
                              size_t ws_size, hipStream_t stream) {
  const float* x = (const float*)d_in[0];
  const float* y = (const float*)d_in[1];
  float* out = (float*)d_out;

  const int npts = out_size / (BATCH * (3 + CHAN));

  // workspace layout:
  char* w = (char*)d_ws;
  float4* packed = (float4*)w;               // B*N float4 = 2 MB
  w += sizeof(float4) * (size_t)BATCH * NPTS;
  u64* pkey = (u64*)w;                       // B*S*16*N u64 = 16.78 MB
  w += sizeof(u64) * (size_t)BATCH * SPLIT * KNN * NPTS;
  float* score = (float*)w;                  // B*N f32
  w += sizeof(float) * (size_t)BATCH * NPTS;
  int* sel = (int*)w;                        // B*npts i32

  pack_kernel<<<BATCH * NPTS / 256, 256, 0, stream>>>(x, packed);
  knn_partial_kernel<<<BATCH * (NPTS / PTILE) * SPLIT, 256, 0, stream>>>(
      packed, pkey);
  merge_score_kernel<<<BATCH * (NPTS / 64), 256, 0, stream>>>(x, pkey, score);
  rank_scatter_kernel<<<BATCH * (NPTS / 128), 256, 0, stream>>>(score, sel,
                                                                npts);
  const int total0 = BATCH * 3 * npts;
  gather_kernel<<<(out_size + 255) / 256, 256, 0, stream>>>(
      x, y, sel, out, npts, total0, out_size);
}